// Round 2
// baseline (918.995 us; speedup 1.0000x reference)
//
#include <hip/hip_runtime.h>

// ---------------------------------------------------------------------------
// GCN link predictor, fp32.
// Pipeline: degree+CSR build -> XW1 -> agg+relu -> H1W2 -> agg -> PQ=H2@Wcat
//           -> per-edge light MLP (gather P[s]+Q[d], relu, dot w2).
// Key algebraic rewrite: z@Wm1 = H2[s]@Wm1[0:64] + H2[d]@Wm1[64:128], so the
// 9.9GF edge-wise GEMM collapses to a 0.82GF node-wise GEMM + cheap edge op.
// ---------------------------------------------------------------------------

__global__ void count_deg_k(const int* __restrict__ dst, int* __restrict__ cnt, int E) {
    int i = blockIdx.x * 256 + threadIdx.x;
    if (i < E) atomicAdd(&cnt[dst[i]], 1);
}

__global__ void dinv_k(const int* __restrict__ cnt, float* __restrict__ dinv, int n) {
    int i = blockIdx.x * 256 + threadIdx.x;
    if (i < n) dinv[i] = rsqrtf((float)cnt[i] + 1.0f);  // +1 = self-loop
}

// Block-level exclusive scan (1024 elems/block of 256 threads, 4 per thread).
__global__ void scan1_k(const int* __restrict__ cnt, int* __restrict__ excl,
                        int* __restrict__ bsum, int n) {
    __shared__ int sd[256];
    int t = threadIdx.x;
    int base = blockIdx.x * 1024 + t * 4;
    int v0 = 0, v1 = 0, v2 = 0, v3 = 0;
    if (base + 0 < n) v0 = cnt[base + 0];
    if (base + 1 < n) v1 = cnt[base + 1];
    if (base + 2 < n) v2 = cnt[base + 2];
    if (base + 3 < n) v3 = cnt[base + 3];
    int sum = v0 + v1 + v2 + v3;
    int acc = sum;
    sd[t] = acc;
    __syncthreads();
    for (int off = 1; off < 256; off <<= 1) {
        int x = (t >= off) ? sd[t - off] : 0;
        __syncthreads();
        acc += x;
        sd[t] = acc;
        __syncthreads();
    }
    int run = acc - sum;  // exclusive prefix of this thread's chunk
    if (base + 0 < n) excl[base + 0] = run;
    run += v0;
    if (base + 1 < n) excl[base + 1] = run;
    run += v1;
    if (base + 2 < n) excl[base + 2] = run;
    run += v2;
    if (base + 3 < n) excl[base + 3] = run;
    if (t == 255) bsum[blockIdx.x] = acc;  // block total
}

__global__ void scan2_k(int* __restrict__ bsum, int nb) {
    __shared__ int sd[256];
    int t = threadIdx.x;
    int v = (t < nb) ? bsum[t] : 0;
    int acc = v;
    sd[t] = acc;
    __syncthreads();
    for (int off = 1; off < 256; off <<= 1) {
        int x = (t >= off) ? sd[t - off] : 0;
        __syncthreads();
        acc += x;
        sd[t] = acc;
        __syncthreads();
    }
    if (t < nb) bsum[t] = acc - v;  // exclusive block offsets
}

__global__ void scan3_k(int* __restrict__ excl, const int* __restrict__ bsum,
                        int* __restrict__ cursor, int n) {
    int i = blockIdx.x * 256 + threadIdx.x;
    if (i < n) {
        int v = excl[i] + bsum[i >> 10];
        excl[i] = v;
        cursor[i] = v;
    }
}

__global__ void scatter_k(const int* __restrict__ src, const int* __restrict__ dst,
                          int* __restrict__ cursor, int* __restrict__ csr_src, int E) {
    int i = blockIdx.x * 256 + threadIdx.x;
    if (i < E) {
        int d = dst[i];
        int p = atomicAdd(&cursor[d], 1);
        csr_src[p] = src[i];
    }
}

// Wcat[64,128]: cols 0:64 = Wm1[0:64,:], cols 64:128 = Wm1[64:128,:].
__global__ void wcat_k(const float* __restrict__ Wm1, float* __restrict__ Wcat) {
    int i = blockIdx.x * 256 + threadIdx.x;
    if (i < 64 * 128) {
        int k = i >> 7, j = i & 127;
        Wcat[i] = (j < 64) ? Wm1[k * 64 + j] : Wm1[(64 + k) * 64 + (j - 64)];
    }
}

// ---------------------------------------------------------------------------
// C[M,NCOL] = A[M,K] @ W[K,NCOL].  Tile 64 rows x NCOL cols.
// Per-thread 4 rows x 8 cols, k-unroll 4. Threads = 16*(NCOL/8).
// ---------------------------------------------------------------------------
template <int NCOL, int K>
__global__ void gemm_k(const float* __restrict__ A, const float* __restrict__ W,
                       float* __restrict__ C, int M) {
    constexpr int CG = NCOL / 8;   // col groups
    constexpr int NT = 16 * CG;    // threads
    __shared__ float Xs[64][68];   // +4 pad: breaks bank conflict on row reads
    __shared__ float Ws[64][NCOL];
    const int t = threadIdx.x;
    const int rg = t / CG;
    const int cg = t % CG;
    const int row0 = blockIdx.x * 64;

    float acc[4][8];
#pragma unroll
    for (int i = 0; i < 4; ++i)
#pragma unroll
        for (int j = 0; j < 8; ++j) acc[i][j] = 0.f;

    for (int kh = 0; kh < K; kh += 64) {
        // stage X tile (64 rows x 64 k)
#pragma unroll
        for (int i = 0; i < 4096 / (NT * 4); ++i) {
            int li = (i * NT + t) * 4;
            int r = li >> 6, c = li & 63;
            int gr = row0 + r;
            if (gr >= M) gr = M - 1;  // clamp; stores guarded
            float4 v = *(const float4*)(A + (size_t)gr * K + kh + c);
            *(float4*)(&Xs[r][c]) = v;
        }
        // stage W tile (64 k x NCOL)
#pragma unroll
        for (int i = 0; i < (64 * NCOL) / (NT * 4); ++i) {
            int li = (i * NT + t) * 4;
            int r = li / NCOL, c = li % NCOL;
            float4 v = *(const float4*)(W + (size_t)(kh + r) * NCOL + c);
            *(float4*)(&Ws[r][c]) = v;
        }
        __syncthreads();

#pragma unroll
        for (int k4 = 0; k4 < 16; ++k4) {
            const int k = k4 * 4;
            float xr[4][4];
#pragma unroll
            for (int i = 0; i < 4; ++i) {
                float4 tmp = *(const float4*)(&Xs[rg * 4 + i][k]);
                xr[i][0] = tmp.x; xr[i][1] = tmp.y; xr[i][2] = tmp.z; xr[i][3] = tmp.w;
            }
#pragma unroll
            for (int kk = 0; kk < 4; ++kk) {
                const float* wr = &Ws[k + kk][cg * 8];
                float wv[8];
#pragma unroll
                for (int j = 0; j < 8; ++j) wv[j] = wr[j];
#pragma unroll
                for (int i = 0; i < 4; ++i) {
                    float x = xr[i][kk];
#pragma unroll
                    for (int j = 0; j < 8; ++j) acc[i][j] = fmaf(x, wv[j], acc[i][j]);
                }
            }
        }
        __syncthreads();
    }

#pragma unroll
    for (int i = 0; i < 4; ++i) {
        int gr = row0 + rg * 4 + i;
        if (gr < M) {
            float* cp = C + (size_t)gr * NCOL + cg * 8;
            float4 v0, v1;
            v0.x = acc[i][0]; v0.y = acc[i][1]; v0.z = acc[i][2]; v0.w = acc[i][3];
            v1.x = acc[i][4]; v1.y = acc[i][5]; v1.z = acc[i][6]; v1.w = acc[i][7];
            *(float4*)cp = v0;
            *(float4*)(cp + 4) = v1;
        }
    }
}

// ---------------------------------------------------------------------------
// GCN aggregation: out[n] = sum_{e:dst=n} dinv[src]*dinv[n]*XW[src]
//                         + dinv[n]^2*XW[n] + bias  (optional ReLU)
// One wave per node; lane covers 2 features (D=128) or 1 (D=64).
// ---------------------------------------------------------------------------
template <int D, bool RELU>
__global__ void agg_k(const float* __restrict__ XW, const float* __restrict__ dinv,
                      const int* __restrict__ row_start, const int* __restrict__ cnt,
                      const int* __restrict__ csr_src, const float* __restrict__ bias,
                      float* __restrict__ out, int n) {
    int wid = (int)((blockIdx.x * blockDim.x + threadIdx.x) >> 6);
    int lane = threadIdx.x & 63;
    if (wid >= n) return;
    float di = dinv[wid];
    int deg = cnt[wid];
    int rs = row_start[wid];
    if constexpr (D == 128) {
        float2 a = ((const float2*)(XW + (size_t)wid * 128))[lane];
        float sn = di * di;
        float ax = a.x * sn, ay = a.y * sn;
        int i = 0;
        for (; i + 2 <= deg; i += 2) {
            int s0 = csr_src[rs + i];
            int s1 = csr_src[rs + i + 1];
            float nm0 = dinv[s0] * di;
            float nm1 = dinv[s1] * di;
            float2 u0 = ((const float2*)(XW + (size_t)s0 * 128))[lane];
            float2 u1 = ((const float2*)(XW + (size_t)s1 * 128))[lane];
            ax = fmaf(u0.x, nm0, ax);
            ay = fmaf(u0.y, nm0, ay);
            ax = fmaf(u1.x, nm1, ax);
            ay = fmaf(u1.y, nm1, ay);
        }
        if (i < deg) {
            int s = csr_src[rs + i];
            float nm = dinv[s] * di;
            float2 v = ((const float2*)(XW + (size_t)s * 128))[lane];
            ax = fmaf(v.x, nm, ax);
            ay = fmaf(v.y, nm, ay);
        }
        float2 b = ((const float2*)bias)[lane];
        ax += b.x;
        ay += b.y;
        if (RELU) { ax = fmaxf(ax, 0.f); ay = fmaxf(ay, 0.f); }
        float2 r; r.x = ax; r.y = ay;
        ((float2*)(out + (size_t)wid * 128))[lane] = r;
    } else {
        float a = XW[(size_t)wid * 64 + lane] * (di * di);
        int i = 0;
        for (; i + 2 <= deg; i += 2) {
            int s0 = csr_src[rs + i];
            int s1 = csr_src[rs + i + 1];
            float v0 = XW[(size_t)s0 * 64 + lane];
            float v1 = XW[(size_t)s1 * 64 + lane];
            a = fmaf(v0, dinv[s0] * di, a);
            a = fmaf(v1, dinv[s1] * di, a);
        }
        if (i < deg) {
            int s = csr_src[rs + i];
            a = fmaf(XW[(size_t)s * 64 + lane], dinv[s] * di, a);
        }
        a += bias[lane];
        if (RELU) a = fmaxf(a, 0.f);
        out[(size_t)wid * 64 + lane] = a;
    }
}

// ---------------------------------------------------------------------------
// Edge MLP (post-rewrite): out[e] = relu(P[s]+Q[d]+bm1) . w2 + b2
// PQ[n][0:64]=P[n], PQ[n][64:128]=Q[n]. 16 lanes per edge, float4 per lane.
// ---------------------------------------------------------------------------
__global__ __launch_bounds__(256) void edge_mlp_k(
    const float* __restrict__ PQ, const int* __restrict__ esrc, const int* __restrict__ edst,
    const float* __restrict__ bm1, const float* __restrict__ w2, const float* __restrict__ bm2,
    float* __restrict__ out, int E) {
    const int lane = threadIdx.x & 63;
    const int sub = lane >> 4;     // which of 4 edges in this wave
    const int q = lane & 15;       // float4 index within the 64-dim row
    const int wid = (int)((blockIdx.x * blockDim.x + threadIdx.x) >> 6);
    const int nw = (int)((gridDim.x * blockDim.x) >> 6);

    const float4 b1v = ((const float4*)bm1)[q];
    const float4 w2v = ((const float4*)w2)[q];
    const float b2 = bm2[0];

    for (int e0 = wid * 4; e0 < E; e0 += nw * 4) {
        int e = e0 + sub;
        bool act = e < E;
        int ee = act ? e : (E - 1);
        int s = esrc[ee];
        int d = edst[ee];
        float4 pv = ((const float4*)(PQ + (size_t)s * 128))[q];
        float4 qv = ((const float4*)(PQ + (size_t)d * 128 + 64))[q];
        float hx = fmaxf(pv.x + qv.x + b1v.x, 0.f);
        float hy = fmaxf(pv.y + qv.y + b1v.y, 0.f);
        float hz = fmaxf(pv.z + qv.z + b1v.z, 0.f);
        float hw = fmaxf(pv.w + qv.w + b1v.w, 0.f);
        float p = fmaf(hx, w2v.x, fmaf(hy, w2v.y, fmaf(hz, w2v.z, hw * w2v.w)));
        p += __shfl_xor(p, 8, 16);
        p += __shfl_xor(p, 4, 16);
        p += __shfl_xor(p, 2, 16);
        p += __shfl_xor(p, 1, 16);
        if (act && q == 0) out[e] = p + b2;
    }
}

// ---------------------------------------------------------------------------

extern "C" void kernel_launch(void* const* d_in, const int* in_sizes, int n_in,
                              void* d_out, int out_size, void* d_ws, size_t ws_size,
                              hipStream_t stream) {
    const float* X   = (const float*)d_in[0];
    const int*  edges = (const int*)d_in[1];
    const float* Wg1 = (const float*)d_in[2];
    const float* bg1 = (const float*)d_in[3];
    const float* Wg2 = (const float*)d_in[4];
    const float* bg2 = (const float*)d_in[5];
    const float* Wm1 = (const float*)d_in[6];
    const float* bm1 = (const float*)d_in[7];
    const float* Wm2 = (const float*)d_in[8];
    const float* bm2 = (const float*)d_in[9];
    float* out = (float*)d_out;

    const int N = in_sizes[0] / 128;
    const int E = in_sizes[1] / 2;
    const int* esrc = edges;
    const int* edst = edges + E;

    char* p = (char*)d_ws;
    auto alloc = [&](size_t nbytes) {
        void* r = (void*)p;
        p += (nbytes + 255) & ~(size_t)255;
        return r;
    };
    float* XW1  = (float*)alloc((size_t)N * 128 * 4);   // reused as PQ later
    float* H1   = (float*)alloc((size_t)N * 128 * 4);
    float* HW2  = (float*)alloc((size_t)N * 64 * 4);
    float* H2   = (float*)alloc((size_t)N * 64 * 4);
    float* dinv = (float*)alloc((size_t)N * 4);
    int* cnt    = (int*)alloc((size_t)N * 4);
    int* rowst  = (int*)alloc((size_t)N * 4);
    int* cursor = (int*)alloc((size_t)N * 4);
    int* bsum   = (int*)alloc(1024);
    float* Wcat = (float*)alloc(64 * 128 * 4);
    int* csr    = (int*)alloc((size_t)E * 4);
    (void)ws_size; (void)n_in; (void)out_size;

    float* PQ = XW1;  // XW1 dead after agg1

    const int gE = (E + 255) / 256;
    const int gN = (N + 255) / 256;
    const int nb = (N + 1023) / 1024;
    const int gM = (N + 63) / 64;
    const int gAgg = (N * 64 + 255) / 256;

    hipMemsetAsync(cnt, 0, (size_t)N * 4, stream);
    count_deg_k<<<gE, 256, 0, stream>>>(edst, cnt, E);
    dinv_k<<<gN, 256, 0, stream>>>(cnt, dinv, N);
    scan1_k<<<nb, 256, 0, stream>>>(cnt, rowst, bsum, N);
    scan2_k<<<1, 256, 0, stream>>>(bsum, nb);
    scan3_k<<<gN, 256, 0, stream>>>(rowst, bsum, cursor, N);
    scatter_k<<<gE, 256, 0, stream>>>(esrc, edst, cursor, csr, E);
    wcat_k<<<32, 256, 0, stream>>>(Wm1, Wcat);

    gemm_k<128, 128><<<gM, 256, 0, stream>>>(X, Wg1, XW1, N);
    agg_k<128, true><<<gAgg, 256, 0, stream>>>(XW1, dinv, rowst, cnt, csr, bg1, H1, N);
    gemm_k<64, 128><<<gM, 128, 0, stream>>>(H1, Wg2, HW2, N);
    agg_k<64, false><<<gAgg, 256, 0, stream>>>(HW2, dinv, rowst, cnt, csr, bg2, H2, N);
    gemm_k<128, 64><<<gM, 256, 0, stream>>>(H2, Wcat, PQ, N);
    edge_mlp_k<<<2048, 256, 0, stream>>>(PQ, esrc, edst, bm1, Wm2, bm2, out, E);
}

// Round 3
// 359.985 us; speedup vs baseline: 2.5529x; 2.5529x over previous
//
#include <hip/hip_runtime.h>

// ---------------------------------------------------------------------------
// GCN link predictor, fp32.
// Algebraic folds:
//   (1) z@Wm1 = H2[s]@Wm1[0:64] + H2[d]@Wm1[64:128]  (edge GEMM -> node GEMM)
//   (2) agg is linear => PQ = agg(H1@(Wg2@Wcat)) + bg2@Wcat  (no PQ gemm)
//   (3) symmetric norm folded: XW' = dinv[n]*(XW)[n] in gemm epilogue, so agg
//       inner loop is index-gather + row-gather + add only.
// Pipeline: CSR build | Wfold precompute -> gemm(X,Wg1)*dinv -> agg+relu ->
//           gemm(H1,Wfold)*dinv -> agg+bcat -> edge op.
// ---------------------------------------------------------------------------

__global__ void count_deg_k(const int* __restrict__ dst, int* __restrict__ cnt, int E) {
    int i = blockIdx.x * 256 + threadIdx.x;
    if (i < E) atomicAdd(&cnt[dst[i]], 1);
}

__global__ void dinv_k(const int* __restrict__ cnt, float* __restrict__ dinv, int n) {
    int i = blockIdx.x * 256 + threadIdx.x;
    if (i < n) dinv[i] = rsqrtf((float)cnt[i] + 1.0f);  // +1 = self-loop
}

// Block-level exclusive scan (1024 elems/block of 256 threads, 4 per thread).
__global__ void scan1_k(const int* __restrict__ cnt, int* __restrict__ excl,
                        int* __restrict__ bsum, int n) {
    __shared__ int sd[256];
    int t = threadIdx.x;
    int base = blockIdx.x * 1024 + t * 4;
    int v0 = 0, v1 = 0, v2 = 0, v3 = 0;
    if (base + 0 < n) v0 = cnt[base + 0];
    if (base + 1 < n) v1 = cnt[base + 1];
    if (base + 2 < n) v2 = cnt[base + 2];
    if (base + 3 < n) v3 = cnt[base + 3];
    int sum = v0 + v1 + v2 + v3;
    int acc = sum;
    sd[t] = acc;
    __syncthreads();
    for (int off = 1; off < 256; off <<= 1) {
        int x = (t >= off) ? sd[t - off] : 0;
        __syncthreads();
        acc += x;
        sd[t] = acc;
        __syncthreads();
    }
    int run = acc - sum;
    if (base + 0 < n) excl[base + 0] = run;
    run += v0;
    if (base + 1 < n) excl[base + 1] = run;
    run += v1;
    if (base + 2 < n) excl[base + 2] = run;
    run += v2;
    if (base + 3 < n) excl[base + 3] = run;
    if (t == 255) bsum[blockIdx.x] = acc;
}

__global__ void scan2_k(int* __restrict__ bsum, int nb) {
    __shared__ int sd[256];
    int t = threadIdx.x;
    int v = (t < nb) ? bsum[t] : 0;
    int acc = v;
    sd[t] = acc;
    __syncthreads();
    for (int off = 1; off < 256; off <<= 1) {
        int x = (t >= off) ? sd[t - off] : 0;
        __syncthreads();
        acc += x;
        sd[t] = acc;
        __syncthreads();
    }
    if (t < nb) bsum[t] = acc - v;
}

__global__ void scan3_k(int* __restrict__ excl, const int* __restrict__ bsum,
                        int* __restrict__ cursor, int n) {
    int i = blockIdx.x * 256 + threadIdx.x;
    if (i < n) {
        int v = excl[i] + bsum[i >> 10];
        excl[i] = v;
        cursor[i] = v;
    }
}

__global__ void scatter_k(const int* __restrict__ src, const int* __restrict__ dst,
                          int* __restrict__ cursor, int* __restrict__ csr_src, int E) {
    int i = blockIdx.x * 256 + threadIdx.x;
    if (i < E) {
        int d = dst[i];
        int p = atomicAdd(&cursor[d], 1);
        csr_src[p] = src[i];
    }
}

// Wfold[128][128] = Wg2 @ Wcat, bcat[128] = bg2 @ Wcat,
// where Wcat[j][c] = (c<64) ? Wm1[j][c] : Wm1[64+j][c-64].
__global__ void wfold_k(const float* __restrict__ Wg2, const float* __restrict__ bg2,
                        const float* __restrict__ Wm1,
                        float* __restrict__ Wfold, float* __restrict__ bcat) {
    int i = blockIdx.x * 256 + threadIdx.x;
    if (i < 128 * 128) {
        int r = i >> 7, c = i & 127;
        const float* wc = (c < 64) ? (Wm1 + c) : (Wm1 + 64 * 64 + (c - 64));
        float acc = 0.f;
#pragma unroll 8
        for (int j = 0; j < 64; ++j) acc = fmaf(Wg2[r * 64 + j], wc[j * 64], acc);
        Wfold[i] = acc;
    } else if (i < 128 * 128 + 128) {
        int c = i - 128 * 128;
        const float* wc = (c < 64) ? (Wm1 + c) : (Wm1 + 64 * 64 + (c - 64));
        float acc = 0.f;
#pragma unroll 8
        for (int j = 0; j < 64; ++j) acc = fmaf(bg2[j], wc[j * 64], acc);
        bcat[c] = acc;
    }
}

// ---------------------------------------------------------------------------
// C[M,128] = rowscale[m] * (A[M,128] @ W[128,128]).  Tile 64 rows.
// Per-thread 4 rows x 8 cols, k-unroll 4. 256 threads.
// ---------------------------------------------------------------------------
__global__ void gemm128_k(const float* __restrict__ A, const float* __restrict__ W,
                          const float* __restrict__ rowscale, float* __restrict__ C, int M) {
    __shared__ float Xs[64][68];
    __shared__ float Ws[64][128];
    const int t = threadIdx.x;
    const int rg = t / 16;
    const int cg = t % 16;
    const int row0 = blockIdx.x * 64;

    float acc[4][8];
#pragma unroll
    for (int i = 0; i < 4; ++i)
#pragma unroll
        for (int j = 0; j < 8; ++j) acc[i][j] = 0.f;

    for (int kh = 0; kh < 128; kh += 64) {
#pragma unroll
        for (int i = 0; i < 4; ++i) {
            int li = (i * 256 + t) * 4;
            int r = li >> 6, c = li & 63;
            int gr = row0 + r;
            if (gr >= M) gr = M - 1;
            float4 v = *(const float4*)(A + (size_t)gr * 128 + kh + c);
            *(float4*)(&Xs[r][c]) = v;
        }
#pragma unroll
        for (int i = 0; i < 8; ++i) {
            int li = (i * 256 + t) * 4;
            int r = li >> 7, c = li & 127;
            float4 v = *(const float4*)(W + (size_t)(kh + r) * 128 + c);
            *(float4*)(&Ws[r][c]) = v;
        }
        __syncthreads();

#pragma unroll
        for (int k4 = 0; k4 < 16; ++k4) {
            const int k = k4 * 4;
            float xr[4][4];
#pragma unroll
            for (int i = 0; i < 4; ++i) {
                float4 tmp = *(const float4*)(&Xs[rg * 4 + i][k]);
                xr[i][0] = tmp.x; xr[i][1] = tmp.y; xr[i][2] = tmp.z; xr[i][3] = tmp.w;
            }
#pragma unroll
            for (int kk = 0; kk < 4; ++kk) {
                const float* wr = &Ws[k + kk][cg * 8];
                float wv[8];
#pragma unroll
                for (int j = 0; j < 8; ++j) wv[j] = wr[j];
#pragma unroll
                for (int i = 0; i < 4; ++i) {
                    float x = xr[i][kk];
#pragma unroll
                    for (int j = 0; j < 8; ++j) acc[i][j] = fmaf(x, wv[j], acc[i][j]);
                }
            }
        }
        __syncthreads();
    }

#pragma unroll
    for (int i = 0; i < 4; ++i) {
        int gr = row0 + rg * 4 + i;
        if (gr < M) {
            float dv = rowscale[gr];
            float* cp = C + (size_t)gr * 128 + cg * 8;
            float4 v0, v1;
            v0.x = acc[i][0] * dv; v0.y = acc[i][1] * dv;
            v0.z = acc[i][2] * dv; v0.w = acc[i][3] * dv;
            v1.x = acc[i][4] * dv; v1.y = acc[i][5] * dv;
            v1.z = acc[i][6] * dv; v1.w = acc[i][7] * dv;
            *(float4*)cp = v0;
            *(float4*)(cp + 4) = v1;
        }
    }
}

// ---------------------------------------------------------------------------
// Aggregation over pre-scaled rows: out[n] = act(di*(XW'[n] + sum XW'[s]) + b)
// One wave per node, lane = 2 features (float2). Gather loop unrolled x4.
// ---------------------------------------------------------------------------
template <bool RELU>
__global__ void agg128_k(const float* __restrict__ XW, const float* __restrict__ dinv,
                         const int* __restrict__ row_start, const int* __restrict__ cnt,
                         const int* __restrict__ csr_src, const float* __restrict__ bias,
                         float* __restrict__ out, int n) {
    int wid = (int)((blockIdx.x * blockDim.x + threadIdx.x) >> 6);
    int lane = threadIdx.x & 63;
    if (wid >= n) return;
    float di = dinv[wid];
    int deg = cnt[wid];
    int rs = row_start[wid];
    const float2* base = (const float2*)XW;
    float2 a = base[(size_t)wid * 64 + lane];
    float ax = a.x, ay = a.y;
    int i = 0;
    for (; i + 4 <= deg; i += 4) {
        int s0 = csr_src[rs + i + 0];
        int s1 = csr_src[rs + i + 1];
        int s2 = csr_src[rs + i + 2];
        int s3 = csr_src[rs + i + 3];
        float2 u0 = base[(size_t)s0 * 64 + lane];
        float2 u1 = base[(size_t)s1 * 64 + lane];
        float2 u2 = base[(size_t)s2 * 64 + lane];
        float2 u3 = base[(size_t)s3 * 64 + lane];
        ax += (u0.x + u1.x) + (u2.x + u3.x);
        ay += (u0.y + u1.y) + (u2.y + u3.y);
    }
    for (; i < deg; ++i) {
        int s = csr_src[rs + i];
        float2 u = base[(size_t)s * 64 + lane];
        ax += u.x;
        ay += u.y;
    }
    float2 b = ((const float2*)bias)[lane];
    ax = fmaf(ax, di, b.x);
    ay = fmaf(ay, di, b.y);
    if (RELU) { ax = fmaxf(ax, 0.f); ay = fmaxf(ay, 0.f); }
    float2 r; r.x = ax; r.y = ay;
    ((float2*)out)[(size_t)wid * 64 + lane] = r;
}

// ---------------------------------------------------------------------------
// Edge op: out[e] = relu(P[s]+Q[d]+bm1) . w2 + b2,  PQ[n] = [P[n] | Q[n]].
// 16 lanes per edge, float4 per lane, 4 edges per wave.
// ---------------------------------------------------------------------------
__global__ __launch_bounds__(256) void edge_mlp_k(
    const float* __restrict__ PQ, const int* __restrict__ esrc, const int* __restrict__ edst,
    const float* __restrict__ bm1, const float* __restrict__ w2, const float* __restrict__ bm2,
    float* __restrict__ out, int E) {
    const int lane = threadIdx.x & 63;
    const int sub = lane >> 4;
    const int q = lane & 15;
    const int wid = (int)((blockIdx.x * blockDim.x + threadIdx.x) >> 6);
    const int nw = (int)((gridDim.x * blockDim.x) >> 6);

    const float4 b1v = ((const float4*)bm1)[q];
    const float4 w2v = ((const float4*)w2)[q];
    const float b2 = bm2[0];

    for (int e0 = wid * 4; e0 < E; e0 += nw * 4) {
        int e = e0 + sub;
        bool act = e < E;
        int ee = act ? e : (E - 1);
        int s = esrc[ee];
        int d = edst[ee];
        float4 pv = ((const float4*)(PQ + (size_t)s * 128))[q];
        float4 qv = ((const float4*)(PQ + (size_t)d * 128 + 64))[q];
        float hx = fmaxf(pv.x + qv.x + b1v.x, 0.f);
        float hy = fmaxf(pv.y + qv.y + b1v.y, 0.f);
        float hz = fmaxf(pv.z + qv.z + b1v.z, 0.f);
        float hw = fmaxf(pv.w + qv.w + b1v.w, 0.f);
        float p = fmaf(hx, w2v.x, fmaf(hy, w2v.y, fmaf(hz, w2v.z, hw * w2v.w)));
        p += __shfl_xor(p, 8, 16);
        p += __shfl_xor(p, 4, 16);
        p += __shfl_xor(p, 2, 16);
        p += __shfl_xor(p, 1, 16);
        if (act && q == 0) out[e] = p + b2;
    }
}

// ---------------------------------------------------------------------------

extern "C" void kernel_launch(void* const* d_in, const int* in_sizes, int n_in,
                              void* d_out, int out_size, void* d_ws, size_t ws_size,
                              hipStream_t stream) {
    const float* X   = (const float*)d_in[0];
    const int*  edges = (const int*)d_in[1];
    const float* Wg1 = (const float*)d_in[2];
    const float* bg1 = (const float*)d_in[3];
    const float* Wg2 = (const float*)d_in[4];
    const float* bg2 = (const float*)d_in[5];
    const float* Wm1 = (const float*)d_in[6];
    const float* bm1 = (const float*)d_in[7];
    const float* Wm2 = (const float*)d_in[8];
    const float* bm2 = (const float*)d_in[9];
    float* out = (float*)d_out;

    const int N = in_sizes[0] / 128;
    const int E = in_sizes[1] / 2;
    const int* esrc = edges;
    const int* edst = edges + E;

    char* p = (char*)d_ws;
    auto alloc = [&](size_t nbytes) {
        void* r = (void*)p;
        p += (nbytes + 255) & ~(size_t)255;
        return r;
    };
    float* bufA  = (float*)alloc((size_t)N * 128 * 4);  // XW1', later G'
    float* bufB  = (float*)alloc((size_t)N * 128 * 4);  // H1, later PQ
    float* dinv  = (float*)alloc((size_t)N * 4);
    int* cnt     = (int*)alloc((size_t)N * 4);
    int* rowst   = (int*)alloc((size_t)N * 4);
    int* cursor  = (int*)alloc((size_t)N * 4);
    int* bsum    = (int*)alloc(1024);
    float* Wfold = (float*)alloc(128 * 128 * 4);
    float* bcat  = (float*)alloc(128 * 4);
    int* csr     = (int*)alloc((size_t)E * 4);
    (void)ws_size; (void)n_in; (void)out_size;

    const int gE = (E + 255) / 256;
    const int gN = (N + 255) / 256;
    const int nb = (N + 1023) / 1024;
    const int gM = (N + 63) / 64;
    const int gAgg = (N * 64 + 255) / 256;

    hipMemsetAsync(cnt, 0, (size_t)N * 4, stream);
    count_deg_k<<<gE, 256, 0, stream>>>(edst, cnt, E);
    dinv_k<<<gN, 256, 0, stream>>>(cnt, dinv, N);
    scan1_k<<<nb, 256, 0, stream>>>(cnt, rowst, bsum, N);
    scan2_k<<<1, 256, 0, stream>>>(bsum, nb);
    scan3_k<<<gN, 256, 0, stream>>>(rowst, bsum, cursor, N);
    scatter_k<<<gE, 256, 0, stream>>>(esrc, edst, cursor, csr, E);
    wfold_k<<<65, 256, 0, stream>>>(Wg2, bg2, Wm1, Wfold, bcat);

    // XW1' = dinv * (X @ Wg1)
    gemm128_k<<<gM, 256, 0, stream>>>(X, Wg1, dinv, bufA, N);
    // H1 = relu(dinv*(self+sum) + bg1)
    agg128_k<true><<<gAgg, 256, 0, stream>>>(bufA, dinv, rowst, cnt, csr, bg1, bufB, N);
    // G' = dinv * (H1 @ Wfold)
    gemm128_k<<<gM, 256, 0, stream>>>(bufB, Wfold, dinv, bufA, N);
    // PQ = dinv*(self+sum) + bcat
    agg128_k<false><<<gAgg, 256, 0, stream>>>(bufA, dinv, rowst, cnt, csr, bcat, bufB, N);
    // out = relu(P[s]+Q[d]+bm1).w2 + b2
    edge_mlp_k<<<2048, 256, 0, stream>>>(bufB, esrc, edst, bm1, Wm2, bm2, out, E);
}

// Round 4
// 356.126 us; speedup vs baseline: 2.5805x; 1.0108x over previous
//
#include <hip/hip_runtime.h>

// ---------------------------------------------------------------------------
// GCN link predictor, fp32.
// Algebraic folds:
//   (1) z@Wm1 = H2[s]@Wm1[0:64] + H2[d]@Wm1[64:128]  (edge GEMM -> node GEMM)
//   (2) agg is linear => PQ = agg(H1@(Wg2@Wcat)) + bg2@Wcat  (no PQ gemm)
//   (3) symmetric norm folded: XW' = dinv[n]*(XW)[n] in gemm epilogue.
// Structure this round:
//   - agg: wave-chunked index broadcast (1 coalesced load / 64 edges) + 8-deep
//     gather unroll for latency hiding.
//   - edge MLP: per-dst-node processing via CSR(src,eid): Q[d] in regs, only
//     P[s] gathered (256B/edge instead of 512B).
// ---------------------------------------------------------------------------

__global__ void count_deg_k(const int* __restrict__ dst, int* __restrict__ cnt, int E) {
    int i = blockIdx.x * 256 + threadIdx.x;
    if (i < E) atomicAdd(&cnt[dst[i]], 1);
}

__global__ void dinv_k(const int* __restrict__ cnt, float* __restrict__ dinv, int n) {
    int i = blockIdx.x * 256 + threadIdx.x;
    if (i < n) dinv[i] = rsqrtf((float)cnt[i] + 1.0f);  // +1 = self-loop
}

// Block-level exclusive scan (1024 elems/block of 256 threads, 4 per thread).
__global__ void scan1_k(const int* __restrict__ cnt, int* __restrict__ excl,
                        int* __restrict__ bsum, int n) {
    __shared__ int sd[256];
    int t = threadIdx.x;
    int base = blockIdx.x * 1024 + t * 4;
    int v0 = 0, v1 = 0, v2 = 0, v3 = 0;
    if (base + 0 < n) v0 = cnt[base + 0];
    if (base + 1 < n) v1 = cnt[base + 1];
    if (base + 2 < n) v2 = cnt[base + 2];
    if (base + 3 < n) v3 = cnt[base + 3];
    int sum = v0 + v1 + v2 + v3;
    int acc = sum;
    sd[t] = acc;
    __syncthreads();
    for (int off = 1; off < 256; off <<= 1) {
        int x = (t >= off) ? sd[t - off] : 0;
        __syncthreads();
        acc += x;
        sd[t] = acc;
        __syncthreads();
    }
    int run = acc - sum;
    if (base + 0 < n) excl[base + 0] = run;
    run += v0;
    if (base + 1 < n) excl[base + 1] = run;
    run += v1;
    if (base + 2 < n) excl[base + 2] = run;
    run += v2;
    if (base + 3 < n) excl[base + 3] = run;
    if (t == 255) bsum[blockIdx.x] = acc;
}

__global__ void scan2_k(int* __restrict__ bsum, int nb) {
    __shared__ int sd[256];
    int t = threadIdx.x;
    int v = (t < nb) ? bsum[t] : 0;
    int acc = v;
    sd[t] = acc;
    __syncthreads();
    for (int off = 1; off < 256; off <<= 1) {
        int x = (t >= off) ? sd[t - off] : 0;
        __syncthreads();
        acc += x;
        sd[t] = acc;
        __syncthreads();
    }
    if (t < nb) bsum[t] = acc - v;
}

__global__ void scan3_k(int* __restrict__ excl, const int* __restrict__ bsum,
                        int* __restrict__ cursor, int n) {
    int i = blockIdx.x * 256 + threadIdx.x;
    if (i < n) {
        int v = excl[i] + bsum[i >> 10];
        excl[i] = v;
        cursor[i] = v;
    }
}

__global__ void scatter_k(const int* __restrict__ src, const int* __restrict__ dst,
                          int* __restrict__ cursor, int2* __restrict__ csr_se, int E) {
    int i = blockIdx.x * 256 + threadIdx.x;
    if (i < E) {
        int d = dst[i];
        int p = atomicAdd(&cursor[d], 1);
        int2 se; se.x = src[i]; se.y = i;
        csr_se[p] = se;
    }
}

// Wfold[128][128] = Wg2 @ Wcat, bcat[128] = bg2 @ Wcat,
// where Wcat[j][c] = (c<64) ? Wm1[j][c] : Wm1[64+j][c-64].
__global__ void wfold_k(const float* __restrict__ Wg2, const float* __restrict__ bg2,
                        const float* __restrict__ Wm1,
                        float* __restrict__ Wfold, float* __restrict__ bcat) {
    int i = blockIdx.x * 256 + threadIdx.x;
    if (i < 128 * 128) {
        int r = i >> 7, c = i & 127;
        const float* wc = (c < 64) ? (Wm1 + c) : (Wm1 + 64 * 64 + (c - 64));
        float acc = 0.f;
#pragma unroll 8
        for (int j = 0; j < 64; ++j) acc = fmaf(Wg2[r * 64 + j], wc[j * 64], acc);
        Wfold[i] = acc;
    } else if (i < 128 * 128 + 128) {
        int c = i - 128 * 128;
        const float* wc = (c < 64) ? (Wm1 + c) : (Wm1 + 64 * 64 + (c - 64));
        float acc = 0.f;
#pragma unroll 8
        for (int j = 0; j < 64; ++j) acc = fmaf(bg2[j], wc[j * 64], acc);
        bcat[c] = acc;
    }
}

// ---------------------------------------------------------------------------
// C[M,128] = rowscale[m] * (A[M,128] @ W[128,128]).  Tile 64 rows.
// ---------------------------------------------------------------------------
__global__ void gemm128_k(const float* __restrict__ A, const float* __restrict__ W,
                          const float* __restrict__ rowscale, float* __restrict__ C, int M) {
    __shared__ float Xs[64][68];
    __shared__ float Ws[64][128];
    const int t = threadIdx.x;
    const int rg = t / 16;
    const int cg = t % 16;
    const int row0 = blockIdx.x * 64;

    float acc[4][8];
#pragma unroll
    for (int i = 0; i < 4; ++i)
#pragma unroll
        for (int j = 0; j < 8; ++j) acc[i][j] = 0.f;

    for (int kh = 0; kh < 128; kh += 64) {
#pragma unroll
        for (int i = 0; i < 4; ++i) {
            int li = (i * 256 + t) * 4;
            int r = li >> 6, c = li & 63;
            int gr = row0 + r;
            if (gr >= M) gr = M - 1;
            float4 v = *(const float4*)(A + (size_t)gr * 128 + kh + c);
            *(float4*)(&Xs[r][c]) = v;
        }
#pragma unroll
        for (int i = 0; i < 8; ++i) {
            int li = (i * 256 + t) * 4;
            int r = li >> 7, c = li & 127;
            float4 v = *(const float4*)(W + (size_t)(kh + r) * 128 + c);
            *(float4*)(&Ws[r][c]) = v;
        }
        __syncthreads();

#pragma unroll
        for (int k4 = 0; k4 < 16; ++k4) {
            const int k = k4 * 4;
            float xr[4][4];
#pragma unroll
            for (int i = 0; i < 4; ++i) {
                float4 tmp = *(const float4*)(&Xs[rg * 4 + i][k]);
                xr[i][0] = tmp.x; xr[i][1] = tmp.y; xr[i][2] = tmp.z; xr[i][3] = tmp.w;
            }
#pragma unroll
            for (int kk = 0; kk < 4; ++kk) {
                const float* wr = &Ws[k + kk][cg * 8];
                float wv[8];
#pragma unroll
                for (int j = 0; j < 8; ++j) wv[j] = wr[j];
#pragma unroll
                for (int i = 0; i < 4; ++i) {
                    float x = xr[i][kk];
#pragma unroll
                    for (int j = 0; j < 8; ++j) acc[i][j] = fmaf(x, wv[j], acc[i][j]);
                }
            }
        }
        __syncthreads();
    }

#pragma unroll
    for (int i = 0; i < 4; ++i) {
        int gr = row0 + rg * 4 + i;
        if (gr < M) {
            float dv = rowscale[gr];
            float* cp = C + (size_t)gr * 128 + cg * 8;
            float4 v0, v1;
            v0.x = acc[i][0] * dv; v0.y = acc[i][1] * dv;
            v0.z = acc[i][2] * dv; v0.w = acc[i][3] * dv;
            v1.x = acc[i][4] * dv; v1.y = acc[i][5] * dv;
            v1.z = acc[i][6] * dv; v1.w = acc[i][7] * dv;
            *(float4*)cp = v0;
            *(float4*)(cp + 4) = v1;
        }
    }
}

// ---------------------------------------------------------------------------
// Aggregation over pre-scaled rows: out[n] = act(di*(XW'[n] + sum XW'[s]) + b)
// One wave per node, lane = 2 features (float2). Indices loaded 64-at-a-time
// (coalesced) and broadcast via shfl; 8 gathers kept in flight.
// ---------------------------------------------------------------------------
template <bool RELU>
__global__ void agg128_k(const float* __restrict__ XW, const float* __restrict__ dinv,
                         const int* __restrict__ row_start, const int* __restrict__ cnt,
                         const int2* __restrict__ csr_se, const float* __restrict__ bias,
                         float* __restrict__ out, int n) {
    int wid = (int)((blockIdx.x * blockDim.x + threadIdx.x) >> 6);
    int lane = threadIdx.x & 63;
    if (wid >= n) return;
    float di = dinv[wid];
    int deg = cnt[wid];
    int rs = row_start[wid];
    const float2* base = (const float2*)XW;
    float2 a = base[(size_t)wid * 64 + lane];
    float ax = a.x, ay = a.y;
    int i = 0;
    while (i < deg) {
        int take = deg - i;
        if (take > 64) take = 64;
        int addr = rs + i + lane;
        int lim = rs + deg - 1;
        if (addr > lim) addr = lim;
        int vidx = csr_se[addr].x;
        int j = 0;
        for (; j + 8 <= take; j += 8) {
            int s0 = __shfl(vidx, j + 0), s1 = __shfl(vidx, j + 1);
            int s2 = __shfl(vidx, j + 2), s3 = __shfl(vidx, j + 3);
            int s4 = __shfl(vidx, j + 4), s5 = __shfl(vidx, j + 5);
            int s6 = __shfl(vidx, j + 6), s7 = __shfl(vidx, j + 7);
            float2 u0 = base[(size_t)s0 * 64 + lane];
            float2 u1 = base[(size_t)s1 * 64 + lane];
            float2 u2 = base[(size_t)s2 * 64 + lane];
            float2 u3 = base[(size_t)s3 * 64 + lane];
            float2 u4 = base[(size_t)s4 * 64 + lane];
            float2 u5 = base[(size_t)s5 * 64 + lane];
            float2 u6 = base[(size_t)s6 * 64 + lane];
            float2 u7 = base[(size_t)s7 * 64 + lane];
            ax += ((u0.x + u1.x) + (u2.x + u3.x)) + ((u4.x + u5.x) + (u6.x + u7.x));
            ay += ((u0.y + u1.y) + (u2.y + u3.y)) + ((u4.y + u5.y) + (u6.y + u7.y));
        }
        for (; j + 4 <= take; j += 4) {
            int s0 = __shfl(vidx, j + 0), s1 = __shfl(vidx, j + 1);
            int s2 = __shfl(vidx, j + 2), s3 = __shfl(vidx, j + 3);
            float2 u0 = base[(size_t)s0 * 64 + lane];
            float2 u1 = base[(size_t)s1 * 64 + lane];
            float2 u2 = base[(size_t)s2 * 64 + lane];
            float2 u3 = base[(size_t)s3 * 64 + lane];
            ax += (u0.x + u1.x) + (u2.x + u3.x);
            ay += (u0.y + u1.y) + (u2.y + u3.y);
        }
        for (; j + 2 <= take; j += 2) {
            int s0 = __shfl(vidx, j + 0), s1 = __shfl(vidx, j + 1);
            float2 u0 = base[(size_t)s0 * 64 + lane];
            float2 u1 = base[(size_t)s1 * 64 + lane];
            ax += u0.x + u1.x;
            ay += u0.y + u1.y;
        }
        if (j < take) {
            int s = __shfl(vidx, j);
            float2 u = base[(size_t)s * 64 + lane];
            ax += u.x;
            ay += u.y;
        }
        i += take;
    }
    float2 b = ((const float2*)bias)[lane];
    ax = fmaf(ax, di, b.x);
    ay = fmaf(ay, di, b.y);
    if (RELU) { ax = fmaxf(ax, 0.f); ay = fmaxf(ay, 0.f); }
    float2 r; r.x = ax; r.y = ay;
    ((float2*)out)[(size_t)wid * 64 + lane] = r;
}

// ---------------------------------------------------------------------------
// Edge op, per-dst-node: wave owns node d; Q[d]+bm1 in regs; for each incoming
// edge gather P[s] (256B), relu, dot w2, write out[eid]. 4 edges per wave
// iteration (16 lanes each), 2 iterations in flight.
// ---------------------------------------------------------------------------
__global__ __launch_bounds__(256) void edge_mlp2_k(
    const float* __restrict__ PQ, const int* __restrict__ row_start,
    const int* __restrict__ cnt, const int2* __restrict__ csr_se,
    const float* __restrict__ bm1, const float* __restrict__ w2,
    const float* __restrict__ bm2, float* __restrict__ out, int n) {
    int wid = (int)((blockIdx.x * blockDim.x + threadIdx.x) >> 6);
    int lane = threadIdx.x & 63;
    if (wid >= n) return;
    int deg = cnt[wid];
    if (deg == 0) return;
    int rs = row_start[wid];
    const int sub = lane >> 4;
    const int q = lane & 15;

    const float4 b1v = ((const float4*)bm1)[q];
    const float4 w2v = ((const float4*)w2)[q];
    const float b2 = bm2[0];
    float4 Qv = *(const float4*)(PQ + (size_t)wid * 128 + 64 + q * 4);
    float4 bq;
    bq.x = Qv.x + b1v.x; bq.y = Qv.y + b1v.y;
    bq.z = Qv.z + b1v.z; bq.w = Qv.w + b1v.w;

    int i = 0;
    while (i < deg) {
        int take = deg - i;
        if (take > 64) take = 64;
        int addr = rs + i + lane;
        int lim = rs + deg - 1;
        if (addr > lim) addr = lim;
        int2 se = csr_se[addr];
        for (int j = 0; j < take; j += 8) {
            int ia = j + sub;
            int ib = j + 4 + sub;
            bool aa = ia < take;
            bool ab = ib < take;
            int sa = __shfl(se.x, aa ? ia : 0);
            int ea = __shfl(se.y, aa ? ia : 0);
            int sb = __shfl(se.x, ab ? ib : 0);
            int eb = __shfl(se.y, ab ? ib : 0);
            float4 pa = *(const float4*)(PQ + (size_t)sa * 128 + q * 4);
            float4 pb = *(const float4*)(PQ + (size_t)sb * 128 + q * 4);
            float ha0 = fmaxf(pa.x + bq.x, 0.f);
            float ha1 = fmaxf(pa.y + bq.y, 0.f);
            float ha2 = fmaxf(pa.z + bq.z, 0.f);
            float ha3 = fmaxf(pa.w + bq.w, 0.f);
            float hb0 = fmaxf(pb.x + bq.x, 0.f);
            float hb1 = fmaxf(pb.y + bq.y, 0.f);
            float hb2 = fmaxf(pb.z + bq.z, 0.f);
            float hb3 = fmaxf(pb.w + bq.w, 0.f);
            float va = fmaf(ha0, w2v.x, fmaf(ha1, w2v.y, fmaf(ha2, w2v.z, ha3 * w2v.w)));
            float vb = fmaf(hb0, w2v.x, fmaf(hb1, w2v.y, fmaf(hb2, w2v.z, hb3 * w2v.w)));
            va += __shfl_xor(va, 8, 16);
            va += __shfl_xor(va, 4, 16);
            va += __shfl_xor(va, 2, 16);
            va += __shfl_xor(va, 1, 16);
            vb += __shfl_xor(vb, 8, 16);
            vb += __shfl_xor(vb, 4, 16);
            vb += __shfl_xor(vb, 2, 16);
            vb += __shfl_xor(vb, 1, 16);
            if (aa && q == 0) out[ea] = va + b2;
            if (ab && q == 0) out[eb] = vb + b2;
        }
        i += take;
    }
}

// ---------------------------------------------------------------------------

extern "C" void kernel_launch(void* const* d_in, const int* in_sizes, int n_in,
                              void* d_out, int out_size, void* d_ws, size_t ws_size,
                              hipStream_t stream) {
    const float* X   = (const float*)d_in[0];
    const int*  edges = (const int*)d_in[1];
    const float* Wg1 = (const float*)d_in[2];
    const float* bg1 = (const float*)d_in[3];
    const float* Wg2 = (const float*)d_in[4];
    const float* bg2 = (const float*)d_in[5];
    const float* Wm1 = (const float*)d_in[6];
    const float* bm1 = (const float*)d_in[7];
    const float* Wm2 = (const float*)d_in[8];
    const float* bm2 = (const float*)d_in[9];
    float* out = (float*)d_out;

    const int N = in_sizes[0] / 128;
    const int E = in_sizes[1] / 2;
    const int* esrc = edges;
    const int* edst = edges + E;

    char* p = (char*)d_ws;
    auto alloc = [&](size_t nbytes) {
        void* r = (void*)p;
        p += (nbytes + 255) & ~(size_t)255;
        return r;
    };
    float* bufA  = (float*)alloc((size_t)N * 128 * 4);  // XW1', later G'
    float* bufB  = (float*)alloc((size_t)N * 128 * 4);  // H1, later PQ
    float* dinv  = (float*)alloc((size_t)N * 4);
    int* cnt     = (int*)alloc((size_t)N * 4);
    int* rowst   = (int*)alloc((size_t)N * 4);
    int* cursor  = (int*)alloc((size_t)N * 4);
    int* bsum    = (int*)alloc(1024);
    float* Wfold = (float*)alloc(128 * 128 * 4);
    float* bcat  = (float*)alloc(128 * 4);
    int2* csr_se = (int2*)alloc((size_t)E * 8);
    (void)ws_size; (void)n_in; (void)out_size;

    const int gE = (E + 255) / 256;
    const int gN = (N + 255) / 256;
    const int nb = (N + 1023) / 1024;
    const int gM = (N + 63) / 64;
    const int gAgg = (N * 64 + 255) / 256;

    hipMemsetAsync(cnt, 0, (size_t)N * 4, stream);
    count_deg_k<<<gE, 256, 0, stream>>>(edst, cnt, E);
    dinv_k<<<gN, 256, 0, stream>>>(cnt, dinv, N);
    scan1_k<<<nb, 256, 0, stream>>>(cnt, rowst, bsum, N);
    scan2_k<<<1, 256, 0, stream>>>(bsum, nb);
    scan3_k<<<gN, 256, 0, stream>>>(rowst, bsum, cursor, N);
    scatter_k<<<gE, 256, 0, stream>>>(esrc, edst, cursor, csr_se, E);
    wfold_k<<<65, 256, 0, stream>>>(Wg2, bg2, Wm1, Wfold, bcat);

    // XW1' = dinv * (X @ Wg1)
    gemm128_k<<<gM, 256, 0, stream>>>(X, Wg1, dinv, bufA, N);
    // H1 = relu(dinv*(self+sum) + bg1)
    agg128_k<true><<<gAgg, 256, 0, stream>>>(bufA, dinv, rowst, cnt, csr_se, bg1, bufB, N);
    // G' = dinv * (H1 @ Wfold)
    gemm128_k<<<gM, 256, 0, stream>>>(bufB, Wfold, dinv, bufA, N);
    // PQ = dinv*(self+sum) + bcat
    agg128_k<false><<<gAgg, 256, 0, stream>>>(bufA, dinv, rowst, cnt, csr_se, bcat, bufB, N);
    // out[eid] = relu(P[s]+Q[d]+bm1).w2 + b2, iterated per dst node
    edge_mlp2_k<<<gAgg, 256, 0, stream>>>(bufB, rowst, cnt, csr_se, bm1, Wm2, bm2, out, N);
}

// Round 5
// 314.004 us; speedup vs baseline: 2.9267x; 1.1341x over previous
//
#include <hip/hip_runtime.h>

// ---------------------------------------------------------------------------
// GCN link predictor.
// Algebraic folds:
//   (1) z@Wm1 = H2[s]@Wm1[0:64] + H2[d]@Wm1[64:128]  (edge GEMM -> node GEMM)
//   (2) agg linear => PQ = agg(H1@(Wg2@Wcat)) + bg2@Wcat  (no PQ gemm)
//   (3) symmetric norm folded into gemm epilogue (rowscale).
// This round: GEMMs via MFMA bf16 2-way split (hi/lo): A*B ~ AhBh+AhBl+AlBh,
// err ~1e-4 abs << 7.4e-3 threshold. W^T hi/lo staged in LDS (padded rows);
// A hi/lo from global. H1 produced directly as bf16 hi/lo in agg1 epilogue.
// ---------------------------------------------------------------------------

typedef __attribute__((ext_vector_type(8))) short s8v;   // 8 x bf16
typedef __attribute__((ext_vector_type(4))) float f4v;   // mfma accum

__device__ __forceinline__ ushort f2bf(float x) {
    unsigned u = __float_as_uint(x);
    unsigned r = (u + 0x7fffu + ((u >> 16) & 1u)) >> 16;  // RNE
    return (ushort)r;
}
__device__ __forceinline__ float bf2f(ushort h) {
    return __uint_as_float(((unsigned)h) << 16);
}

__global__ void count_deg_k(const int* __restrict__ dst, int* __restrict__ cnt, int E) {
    int i = blockIdx.x * 256 + threadIdx.x;
    if (i < E) atomicAdd(&cnt[dst[i]], 1);
}

__global__ void dinv_k(const int* __restrict__ cnt, float* __restrict__ dinv, int n) {
    int i = blockIdx.x * 256 + threadIdx.x;
    if (i < n) dinv[i] = rsqrtf((float)cnt[i] + 1.0f);  // +1 = self-loop
}

// Block-level exclusive scan (1024 elems/block of 256 threads, 4 per thread).
__global__ void scan1_k(const int* __restrict__ cnt, int* __restrict__ excl,
                        int* __restrict__ bsum, int n) {
    __shared__ int sd[256];
    int t = threadIdx.x;
    int base = blockIdx.x * 1024 + t * 4;
    int v0 = 0, v1 = 0, v2 = 0, v3 = 0;
    if (base + 0 < n) v0 = cnt[base + 0];
    if (base + 1 < n) v1 = cnt[base + 1];
    if (base + 2 < n) v2 = cnt[base + 2];
    if (base + 3 < n) v3 = cnt[base + 3];
    int sum = v0 + v1 + v2 + v3;
    int acc = sum;
    sd[t] = acc;
    __syncthreads();
    for (int off = 1; off < 256; off <<= 1) {
        int x = (t >= off) ? sd[t - off] : 0;
        __syncthreads();
        acc += x;
        sd[t] = acc;
        __syncthreads();
    }
    int run = acc - sum;
    if (base + 0 < n) excl[base + 0] = run;
    run += v0;
    if (base + 1 < n) excl[base + 1] = run;
    run += v1;
    if (base + 2 < n) excl[base + 2] = run;
    run += v2;
    if (base + 3 < n) excl[base + 3] = run;
    if (t == 255) bsum[blockIdx.x] = acc;
}

__global__ void scan2_k(int* __restrict__ bsum, int nb) {
    __shared__ int sd[256];
    int t = threadIdx.x;
    int v = (t < nb) ? bsum[t] : 0;
    int acc = v;
    sd[t] = acc;
    __syncthreads();
    for (int off = 1; off < 256; off <<= 1) {
        int x = (t >= off) ? sd[t - off] : 0;
        __syncthreads();
        acc += x;
        sd[t] = acc;
        __syncthreads();
    }
    if (t < nb) bsum[t] = acc - v;
}

__global__ void scan3_k(int* __restrict__ excl, const int* __restrict__ bsum,
                        int* __restrict__ cursor, int n) {
    int i = blockIdx.x * 256 + threadIdx.x;
    if (i < n) {
        int v = excl[i] + bsum[i >> 10];
        excl[i] = v;
        cursor[i] = v;
    }
}

__global__ void scatter_k(const int* __restrict__ src, const int* __restrict__ dst,
                          int* __restrict__ cursor, int2* __restrict__ csr_se, int E) {
    int i = blockIdx.x * 256 + threadIdx.x;
    if (i < E) {
        int d = dst[i];
        int p = atomicAdd(&cursor[d], 1);
        int2 se; se.x = src[i]; se.y = i;
        csr_se[p] = se;
    }
}

// Split fp32 array into bf16 hi/lo pair (4 elems/thread).
__global__ void split_k(const float* __restrict__ X, ushort* __restrict__ Xh,
                        ushort* __restrict__ Xl, int n4) {
    int i = blockIdx.x * 256 + threadIdx.x;
    if (i >= n4) return;
    float4 v = ((const float4*)X)[i];
    ushort4 h, l;
    h.x = f2bf(v.x); l.x = f2bf(v.x - bf2f(h.x));
    h.y = f2bf(v.y); l.y = f2bf(v.y - bf2f(h.y));
    h.z = f2bf(v.z); l.z = f2bf(v.z - bf2f(h.z));
    h.w = f2bf(v.w); l.w = f2bf(v.w - bf2f(h.w));
    ((ushort4*)Xh)[i] = h;
    ((ushort4*)Xl)[i] = l;
}

// Wg1^T split: Wt[n][k] = Wg1[k][n] -> hi/lo bf16.
__global__ void wtsplit_k(const float* __restrict__ W, ushort* __restrict__ Wth,
                          ushort* __restrict__ Wtl) {
    int i = blockIdx.x * 256 + threadIdx.x;  // 16384
    int n = i >> 7, k = i & 127;
    float x = W[k * 128 + n];
    ushort h = f2bf(x);
    Wth[i] = h;
    Wtl[i] = f2bf(x - bf2f(h));
}

// Wfold^T[c][r] = (Wg2 @ Wcat)[r][c] split hi/lo; bcat = bg2 @ Wcat.
// Wcat[j][c] = (c<64) ? Wm1[j][c] : Wm1[64+j][c-64].
__global__ void wfold_k(const float* __restrict__ Wg2, const float* __restrict__ bg2,
                        const float* __restrict__ Wm1,
                        ushort* __restrict__ Wfth, ushort* __restrict__ Wftl,
                        float* __restrict__ bcat) {
    int i = blockIdx.x * 256 + threadIdx.x;
    if (i < 128 * 128) {
        int r = i >> 7, c = i & 127;  // r = k (H1 feature), c = out col
        const float* wc = (c < 64) ? (Wm1 + c) : (Wm1 + 64 * 64 + (c - 64));
        float acc = 0.f;
#pragma unroll 8
        for (int j = 0; j < 64; ++j) acc = fmaf(Wg2[r * 64 + j], wc[j * 64], acc);
        ushort h = f2bf(acc);
        Wfth[c * 128 + r] = h;
        Wftl[c * 128 + r] = f2bf(acc - bf2f(h));
    } else if (i < 128 * 128 + 128) {
        int c = i - 128 * 128;
        const float* wc = (c < 64) ? (Wm1 + c) : (Wm1 + 64 * 64 + (c - 64));
        float acc = 0.f;
#pragma unroll 8
        for (int j = 0; j < 64; ++j) acc = fmaf(bg2[j], wc[j * 64], acc);
        bcat[c] = acc;
    }
}

// ---------------------------------------------------------------------------
// C[M,128] = rowscale[m] * (A[M,128] @ B[128,128]) via mfma_f32_16x16x32_bf16
// with 2-way split: A=Ah+Al, B=Bh+Bl, A*B ~ AhBh + AhBl + AlBh.
// B given transposed (Bt[n][k], k contiguous), staged hi+lo in LDS with
// 136-short padded rows (2-way bank aliasing only). 4 waves, 16 rows each.
// A frag: lane holds row=lane&15, k = ks*32 + (lane>>4)*8 .. +8 (contiguous).
// B frag: lane holds col=lane&15, same k pattern.  C/D: col=lane&15,
// row=(lane>>4)*4+reg  [m89-verified].
// ---------------------------------------------------------------------------
__global__ __launch_bounds__(256) void mgemm_k(
    const ushort* __restrict__ Ah, const ushort* __restrict__ Al,
    const ushort* __restrict__ Bth, const ushort* __restrict__ Btl,
    const float* __restrict__ rowscale, float* __restrict__ C, int M) {
    __shared__ ushort Bs[2][128][136];
    const int t = threadIdx.x;
#pragma unroll
    for (int i = 0; i < 16; ++i) {
        int c = i * 256 + t;
        int arr = c >> 11;       // 0: hi, 1: lo
        int cc = c & 2047;
        int n = cc >> 4, kb = cc & 15;
        const ushort* src = arr ? Btl : Bth;
        s8v v = *(const s8v*)(src + n * 128 + kb * 8);
        *(s8v*)(&Bs[arr][n][kb * 8]) = v;
    }
    __syncthreads();

    const int lane = t & 63;
    const int w = t >> 6;
    const int r16 = lane & 15;
    const int kg = lane >> 4;  // 0..3
    int arow = blockIdx.x * 64 + w * 16 + r16;
    if (arow >= M) arow = M - 1;
    const ushort* pAh = Ah + (size_t)arow * 128 + kg * 8;
    const ushort* pAl = Al + (size_t)arow * 128 + kg * 8;

    f4v acc[8];
#pragma unroll
    for (int ct = 0; ct < 8; ++ct) acc[ct] = (f4v){0.f, 0.f, 0.f, 0.f};

#pragma unroll
    for (int ks = 0; ks < 4; ++ks) {
        s8v ah = *(const s8v*)(pAh + ks * 32);
        s8v al = *(const s8v*)(pAl + ks * 32);
#pragma unroll
        for (int ct = 0; ct < 8; ++ct) {
            s8v bh = *(const s8v*)(&Bs[0][ct * 16 + r16][ks * 32 + kg * 8]);
            s8v bl = *(const s8v*)(&Bs[1][ct * 16 + r16][ks * 32 + kg * 8]);
            acc[ct] = __builtin_amdgcn_mfma_f32_16x16x32_bf16(ah, bh, acc[ct], 0, 0, 0);
            acc[ct] = __builtin_amdgcn_mfma_f32_16x16x32_bf16(ah, bl, acc[ct], 0, 0, 0);
            acc[ct] = __builtin_amdgcn_mfma_f32_16x16x32_bf16(al, bh, acc[ct], 0, 0, 0);
        }
    }

    const int rbase = blockIdx.x * 64 + w * 16 + kg * 4;
#pragma unroll
    for (int r = 0; r < 4; ++r) {
        int row = rbase + r;
        if (row < M) {
            float sc = rowscale[row];
#pragma unroll
            for (int ct = 0; ct < 8; ++ct)
                C[(size_t)row * 128 + ct * 16 + r16] = acc[ct][r] * sc;
        }
    }
}

// ---------------------------------------------------------------------------
// Aggregation over pre-scaled rows: v = di*(XW'[n] + sum XW'[s]) + b.
// RELU_BF16: relu then emit bf16 hi/lo (for mfma gemm2).  else fp32 out.
// One wave per node, lane = 2 features. Indices broadcast from one coalesced
// 64-wide load; 8 gathers in flight.
// ---------------------------------------------------------------------------
template <bool RELU_BF16>
__global__ void agg128_k(const float* __restrict__ XW, const float* __restrict__ dinv,
                         const int* __restrict__ row_start, const int* __restrict__ cnt,
                         const int2* __restrict__ csr_se, const float* __restrict__ bias,
                         float* __restrict__ outf, ushort* __restrict__ outh,
                         ushort* __restrict__ outl, int n) {
    int wid = (int)((blockIdx.x * blockDim.x + threadIdx.x) >> 6);
    int lane = threadIdx.x & 63;
    if (wid >= n) return;
    float di = dinv[wid];
    int deg = cnt[wid];
    int rs = row_start[wid];
    const float2* base = (const float2*)XW;
    float2 a = base[(size_t)wid * 64 + lane];
    float ax = a.x, ay = a.y;
    int i = 0;
    while (i < deg) {
        int take = deg - i;
        if (take > 64) take = 64;
        int addr = rs + i + lane;
        int lim = rs + deg - 1;
        if (addr > lim) addr = lim;
        int vidx = csr_se[addr].x;
        int j = 0;
        for (; j + 8 <= take; j += 8) {
            int s0 = __shfl(vidx, j + 0), s1 = __shfl(vidx, j + 1);
            int s2 = __shfl(vidx, j + 2), s3 = __shfl(vidx, j + 3);
            int s4 = __shfl(vidx, j + 4), s5 = __shfl(vidx, j + 5);
            int s6 = __shfl(vidx, j + 6), s7 = __shfl(vidx, j + 7);
            float2 u0 = base[(size_t)s0 * 64 + lane];
            float2 u1 = base[(size_t)s1 * 64 + lane];
            float2 u2 = base[(size_t)s2 * 64 + lane];
            float2 u3 = base[(size_t)s3 * 64 + lane];
            float2 u4 = base[(size_t)s4 * 64 + lane];
            float2 u5 = base[(size_t)s5 * 64 + lane];
            float2 u6 = base[(size_t)s6 * 64 + lane];
            float2 u7 = base[(size_t)s7 * 64 + lane];
            ax += ((u0.x + u1.x) + (u2.x + u3.x)) + ((u4.x + u5.x) + (u6.x + u7.x));
            ay += ((u0.y + u1.y) + (u2.y + u3.y)) + ((u4.y + u5.y) + (u6.y + u7.y));
        }
        for (; j + 2 <= take; j += 2) {
            int s0 = __shfl(vidx, j + 0), s1 = __shfl(vidx, j + 1);
            float2 u0 = base[(size_t)s0 * 64 + lane];
            float2 u1 = base[(size_t)s1 * 64 + lane];
            ax += u0.x + u1.x;
            ay += u0.y + u1.y;
        }
        if (j < take) {
            int s = __shfl(vidx, j);
            float2 u = base[(size_t)s * 64 + lane];
            ax += u.x;
            ay += u.y;
        }
        i += take;
    }
    float2 b = ((const float2*)bias)[lane];
    ax = fmaf(ax, di, b.x);
    ay = fmaf(ay, di, b.y);
    if constexpr (RELU_BF16) {
        ax = fmaxf(ax, 0.f);
        ay = fmaxf(ay, 0.f);
        ushort2 h, l;
        h.x = f2bf(ax); l.x = f2bf(ax - bf2f(h.x));
        h.y = f2bf(ay); l.y = f2bf(ay - bf2f(h.y));
        ((ushort2*)outh)[(size_t)wid * 64 + lane] = h;
        ((ushort2*)outl)[(size_t)wid * 64 + lane] = l;
    } else {
        float2 r; r.x = ax; r.y = ay;
        ((float2*)outf)[(size_t)wid * 64 + lane] = r;
    }
}

// ---------------------------------------------------------------------------
// Edge op, per-dst-node: out[eid] = relu(P[s]+Q[d]+bm1).w2 + b2.
// Q[d]+bm1 in regs; only P[s] gathered (256B/edge). 16 lanes/edge.
// ---------------------------------------------------------------------------
__global__ __launch_bounds__(256) void edge_mlp2_k(
    const float* __restrict__ PQ, const int* __restrict__ row_start,
    const int* __restrict__ cnt, const int2* __restrict__ csr_se,
    const float* __restrict__ bm1, const float* __restrict__ w2,
    const float* __restrict__ bm2, float* __restrict__ out, int n) {
    int wid = (int)((blockIdx.x * blockDim.x + threadIdx.x) >> 6);
    int lane = threadIdx.x & 63;
    if (wid >= n) return;
    int deg = cnt[wid];
    if (deg == 0) return;
    int rs = row_start[wid];
    const int sub = lane >> 4;
    const int q = lane & 15;

    const float4 b1v = ((const float4*)bm1)[q];
    const float4 w2v = ((const float4*)w2)[q];
    const float b2 = bm2[0];
    float4 Qv = *(const float4*)(PQ + (size_t)wid * 128 + 64 + q * 4);
    float4 bq;
    bq.x = Qv.x + b1v.x; bq.y = Qv.y + b1v.y;
    bq.z = Qv.z + b1v.z; bq.w = Qv.w + b1v.w;

    int i = 0;
    while (i < deg) {
        int take = deg - i;
        if (take > 64) take = 64;
        int addr = rs + i + lane;
        int lim = rs + deg - 1;
        if (addr > lim) addr = lim;
        int2 se = csr_se[addr];
        for (int j = 0; j < take; j += 8) {
            int ia = j + sub;
            int ib = j + 4 + sub;
            bool aa = ia < take;
            bool ab = ib < take;
            int sa = __shfl(se.x, aa ? ia : 0);
            int ea = __shfl(se.y, aa ? ia : 0);
            int sb = __shfl(se.x, ab ? ib : 0);
            int eb = __shfl(se.y, ab ? ib : 0);
            float4 pa = *(const float4*)(PQ + (size_t)sa * 128 + q * 4);
            float4 pb = *(const float4*)(PQ + (size_t)sb * 128 + q * 4);
            float ha0 = fmaxf(pa.x + bq.x, 0.f);
            float ha1 = fmaxf(pa.y + bq.y, 0.f);
            float ha2 = fmaxf(pa.z + bq.z, 0.f);
            float ha3 = fmaxf(pa.w + bq.w, 0.f);
            float hb0 = fmaxf(pb.x + bq.x, 0.f);
            float hb1 = fmaxf(pb.y + bq.y, 0.f);
            float hb2 = fmaxf(pb.z + bq.z, 0.f);
            float hb3 = fmaxf(pb.w + bq.w, 0.f);
            float va = fmaf(ha0, w2v.x, fmaf(ha1, w2v.y, fmaf(ha2, w2v.z, ha3 * w2v.w)));
            float vb = fmaf(hb0, w2v.x, fmaf(hb1, w2v.y, fmaf(hb2, w2v.z, hb3 * w2v.w)));
            va += __shfl_xor(va, 8, 16);
            va += __shfl_xor(va, 4, 16);
            va += __shfl_xor(va, 2, 16);
            va += __shfl_xor(va, 1, 16);
            vb += __shfl_xor(vb, 8, 16);
            vb += __shfl_xor(vb, 4, 16);
            vb += __shfl_xor(vb, 2, 16);
            vb += __shfl_xor(vb, 1, 16);
            if (aa && q == 0) out[ea] = va + b2;
            if (ab && q == 0) out[eb] = vb + b2;
        }
        i += take;
    }
}

// ---------------------------------------------------------------------------

extern "C" void kernel_launch(void* const* d_in, const int* in_sizes, int n_in,
                              void* d_out, int out_size, void* d_ws, size_t ws_size,
                              hipStream_t stream) {
    const float* X   = (const float*)d_in[0];
    const int*  edges = (const int*)d_in[1];
    const float* Wg1 = (const float*)d_in[2];
    const float* bg1 = (const float*)d_in[3];
    const float* Wg2 = (const float*)d_in[4];
    const float* bg2 = (const float*)d_in[5];
    const float* Wm1 = (const float*)d_in[6];
    const float* bm1 = (const float*)d_in[7];
    const float* Wm2 = (const float*)d_in[8];
    const float* bm2 = (const float*)d_in[9];
    float* out = (float*)d_out;

    const int N = in_sizes[0] / 128;
    const int E = in_sizes[1] / 2;
    const int* esrc = edges;
    const int* edst = edges + E;

    char* p = (char*)d_ws;
    auto alloc = [&](size_t nbytes) {
        void* r = (void*)p;
        p += (nbytes + 255) & ~(size_t)255;
        return r;
    };
    float* bufA   = (float*)alloc((size_t)N * 128 * 4);  // gemm outputs (fp32)
    float* bufB   = (float*)alloc((size_t)N * 128 * 4);  // X/H splits, then PQ
    float* dinv   = (float*)alloc((size_t)N * 4);
    int* cnt      = (int*)alloc((size_t)N * 4);
    int* rowst    = (int*)alloc((size_t)N * 4);
    int* cursor   = (int*)alloc((size_t)N * 4);
    int* bsum     = (int*)alloc(1024);
    ushort* Wg1th = (ushort*)alloc(128 * 128 * 2);
    ushort* Wg1tl = (ushort*)alloc(128 * 128 * 2);
    ushort* Wfth  = (ushort*)alloc(128 * 128 * 2);
    ushort* Wftl  = (ushort*)alloc(128 * 128 * 2);
    float* bcat   = (float*)alloc(128 * 4);
    int2* csr_se  = (int2*)alloc((size_t)E * 8);
    (void)ws_size; (void)n_in; (void)out_size;

    const size_t NF = (size_t)N * 128;
    ushort* Xh = (ushort*)bufB;      // bufB fp32 slot unused until agg2 (PQ)
    ushort* Xl = Xh + NF;            // Xh/Xl dead after gemm1
    ushort* Hh = Xh;                 // Hh/Hl live agg1 -> gemm2, then dead
    ushort* Hl = Xl;

    const int gE = (E + 255) / 256;
    const int gN = (N + 255) / 256;
    const int nb = (N + 1023) / 1024;
    const int gM64 = (N + 63) / 64;
    const int gAgg = (N * 64 + 255) / 256;
    const int n4 = (int)(NF / 4);
    const int gSplit = (n4 + 255) / 256;

    hipMemsetAsync(cnt, 0, (size_t)N * 4, stream);
    count_deg_k<<<gE, 256, 0, stream>>>(edst, cnt, E);
    dinv_k<<<gN, 256, 0, stream>>>(cnt, dinv, N);
    scan1_k<<<nb, 256, 0, stream>>>(cnt, rowst, bsum, N);
    scan2_k<<<1, 256, 0, stream>>>(bsum, nb);
    scan3_k<<<gN, 256, 0, stream>>>(rowst, bsum, cursor, N);
    scatter_k<<<gE, 256, 0, stream>>>(esrc, edst, cursor, csr_se, E);
    wtsplit_k<<<64, 256, 0, stream>>>(Wg1, Wg1th, Wg1tl);
    wfold_k<<<65, 256, 0, stream>>>(Wg2, bg2, Wm1, Wfth, Wftl, bcat);
    split_k<<<gSplit, 256, 0, stream>>>(X, Xh, Xl, n4);

    // bufA = dinv * (X @ Wg1)
    mgemm_k<<<gM64, 256, 0, stream>>>(Xh, Xl, Wg1th, Wg1tl, dinv, bufA, N);
    // H1 = relu(dinv*(self+sum) + bg1) -> bf16 hi/lo
    agg128_k<true><<<gAgg, 256, 0, stream>>>(bufA, dinv, rowst, cnt, csr_se, bg1,
                                             nullptr, Hh, Hl, N);
    // bufA = dinv * (H1 @ Wfold)
    mgemm_k<<<gM64, 256, 0, stream>>>(Hh, Hl, Wfth, Wftl, dinv, bufA, N);
    // PQ = dinv*(self+sum) + bcat  (fp32, bufB)
    agg128_k<false><<<gAgg, 256, 0, stream>>>(bufA, dinv, rowst, cnt, csr_se, bcat,
                                              bufB, nullptr, nullptr, N);
    // out[eid] = relu(P[s]+Q[d]+bm1).w2 + b2
    edge_mlp2_k<<<gAgg, 256, 0, stream>>>(bufB, rowst, cnt, csr_se, bm1, Wm2, bm2, out, N);
}

// Round 8
// 272.374 us; speedup vs baseline: 3.3740x; 1.1528x over previous
//
#include <hip/hip_runtime.h>

// ---------------------------------------------------------------------------
// GCN link predictor (v3 bf16-gather edition).
// Algebraic folds:
//   (1) z@Wm1 = H2[s]@Wm1[0:64] + H2[d]@Wm1[64:128]  (edge GEMM -> node GEMM)
//   (2) agg linear => PQ = agg(H1@(Wg2@Wcat)) + bg2@Wcat  (no PQ gemm)
//   (3) symmetric norm folded into gemm epilogue (rowscale).
// Gathered arrays stored bf16 (agg rows 256B, PQ rows 128B); mgemm reads
// fp32 A and hi/lo-splits in registers; GEMM C written bf16.
// ---------------------------------------------------------------------------

typedef __attribute__((ext_vector_type(8))) short bf8v;  // 8 x bf16
typedef __attribute__((ext_vector_type(4))) float fa4v;  // mfma accum

__device__ __forceinline__ ushort to_bf(float x) {
    unsigned u = __float_as_uint(x);
    unsigned r = (u + 0x7fffu + ((u >> 16) & 1u)) >> 16;  // RNE
    return (ushort)r;
}
__device__ __forceinline__ float from_bf(ushort h) {
    return __uint_as_float(((unsigned)h) << 16);
}

__global__ void deg_count_k(const int* __restrict__ dst, int* __restrict__ cnt, int E) {
    int i = blockIdx.x * 256 + threadIdx.x;
    if (i < E) atomicAdd(&cnt[dst[i]], 1);
}

__global__ void deg_inv_k(const int* __restrict__ cnt, float* __restrict__ dinv, int n) {
    int i = blockIdx.x * 256 + threadIdx.x;
    if (i < n) dinv[i] = rsqrtf((float)cnt[i] + 1.0f);  // +1 = self-loop
}

// Block-level exclusive scan (1024 elems/block of 256 threads, 4 per thread).
__global__ void scan_a_k(const int* __restrict__ cnt, int* __restrict__ excl,
                         int* __restrict__ bsum, int n) {
    __shared__ int sd[256];
    int t = threadIdx.x;
    int base = blockIdx.x * 1024 + t * 4;
    int v0 = 0, v1 = 0, v2 = 0, v3 = 0;
    if (base + 0 < n) v0 = cnt[base + 0];
    if (base + 1 < n) v1 = cnt[base + 1];
    if (base + 2 < n) v2 = cnt[base + 2];
    if (base + 3 < n) v3 = cnt[base + 3];
    int sum = v0 + v1 + v2 + v3;
    int acc = sum;
    sd[t] = acc;
    __syncthreads();
    for (int off = 1; off < 256; off <<= 1) {
        int x = (t >= off) ? sd[t - off] : 0;
        __syncthreads();
        acc += x;
        sd[t] = acc;
        __syncthreads();
    }
    int run = acc - sum;
    if (base + 0 < n) excl[base + 0] = run;
    run += v0;
    if (base + 1 < n) excl[base + 1] = run;
    run += v1;
    if (base + 2 < n) excl[base + 2] = run;
    run += v2;
    if (base + 3 < n) excl[base + 3] = run;
    if (t == 255) bsum[blockIdx.x] = acc;
}

__global__ void scan_b_k(int* __restrict__ bsum, int nb) {
    __shared__ int sd[256];
    int t = threadIdx.x;
    int v = (t < nb) ? bsum[t] : 0;
    int acc = v;
    sd[t] = acc;
    __syncthreads();
    for (int off = 1; off < 256; off <<= 1) {
        int x = (t >= off) ? sd[t - off] : 0;
        __syncthreads();
        acc += x;
        sd[t] = acc;
        __syncthreads();
    }
    if (t < nb) bsum[t] = acc - v;
}

__global__ void scan_c_k(int* __restrict__ excl, const int* __restrict__ bsum,
                         int* __restrict__ cursor, int n) {
    int i = blockIdx.x * 256 + threadIdx.x;
    if (i < n) {
        int v = excl[i] + bsum[i >> 10];
        excl[i] = v;
        cursor[i] = v;
    }
}

__global__ void csr_fill_k(const int* __restrict__ src, const int* __restrict__ dst,
                           int* __restrict__ cursor, int2* __restrict__ csr_se, int E) {
    int i = blockIdx.x * 256 + threadIdx.x;
    if (i < E) {
        int d = dst[i];
        int p = atomicAdd(&cursor[d], 1);
        int2 se; se.x = src[i]; se.y = i;
        csr_se[p] = se;
    }
}

// Wg1^T split: Wt[n][k] = Wg1[k][n] -> hi/lo bf16.
__global__ void w1t_split_k(const float* __restrict__ W, ushort* __restrict__ Wth,
                            ushort* __restrict__ Wtl) {
    int i = blockIdx.x * 256 + threadIdx.x;  // 16384
    int n = i >> 7, k = i & 127;
    float x = W[k * 128 + n];
    ushort h = to_bf(x);
    Wth[i] = h;
    Wtl[i] = to_bf(x - from_bf(h));
}

// Wfold^T[c][r] = (Wg2 @ Wcat)[r][c] split hi/lo; bcat = bg2 @ Wcat.
// Wcat[j][c] = (c<64) ? Wm1[j][c] : Wm1[64+j][c-64].
__global__ void wfold_split_k(const float* __restrict__ Wg2, const float* __restrict__ bg2,
                              const float* __restrict__ Wm1,
                              ushort* __restrict__ Wfth, ushort* __restrict__ Wftl,
                              float* __restrict__ bcat) {
    int i = blockIdx.x * 256 + threadIdx.x;
    if (i < 128 * 128) {
        int r = i >> 7, c = i & 127;  // r = k (H1 feature), c = out col
        const float* wc = (c < 64) ? (Wm1 + c) : (Wm1 + 64 * 64 + (c - 64));
        float acc = 0.f;
#pragma unroll 8
        for (int j = 0; j < 64; ++j) acc = fmaf(Wg2[r * 64 + j], wc[j * 64], acc);
        ushort h = to_bf(acc);
        Wfth[c * 128 + r] = h;
        Wftl[c * 128 + r] = to_bf(acc - from_bf(h));
    } else if (i < 128 * 128 + 128) {
        int c = i - 128 * 128;
        const float* wc = (c < 64) ? (Wm1 + c) : (Wm1 + 64 * 64 + (c - 64));
        float acc = 0.f;
#pragma unroll 8
        for (int j = 0; j < 64; ++j) acc = fmaf(bg2[j], wc[j * 64], acc);
        bcat[c] = acc;
    }
}

// ---------------------------------------------------------------------------
// C[M,128] = bf16( rowscale[m] * (A[M,128] @ B[128,128]) ), A fp32 (split to
// hi/lo bf16 in registers), B^T hi/lo staged in LDS (136-short padded rows).
// mfma_f32_16x16x32_bf16; A*B ~ AhBh + AhBl + AlBh. 4 waves x 16 rows.
// C/D layout: col=lane&15, row=(lane>>4)*4+reg  [m89-verified].
// ---------------------------------------------------------------------------
__global__ __launch_bounds__(256) void gemm_mfma_k(
    const float* __restrict__ A,
    const ushort* __restrict__ Bth, const ushort* __restrict__ Btl,
    const float* __restrict__ rowscale, ushort* __restrict__ C, int M) {
    __shared__ ushort Bs[2][128][136];
    const int t = threadIdx.x;
#pragma unroll
    for (int i = 0; i < 16; ++i) {
        int c = i * 256 + t;
        int arr = c >> 11;       // 0: hi, 1: lo
        int cc = c & 2047;
        int n = cc >> 4, kb = cc & 15;
        const ushort* src = arr ? Btl : Bth;
        bf8v v = *(const bf8v*)(src + n * 128 + kb * 8);
        *(bf8v*)(&Bs[arr][n][kb * 8]) = v;
    }
    __syncthreads();

    const int lane = t & 63;
    const int w = t >> 6;
    const int r16 = lane & 15;
    const int kg = lane >> 4;  // 0..3
    int arow = blockIdx.x * 64 + w * 16 + r16;
    if (arow >= M) arow = M - 1;
    const float* pA = A + (size_t)arow * 128 + kg * 8;

    fa4v acc[8];
#pragma unroll
    for (int ct = 0; ct < 8; ++ct) acc[ct] = (fa4v){0.f, 0.f, 0.f, 0.f};

#pragma unroll
    for (int ks = 0; ks < 4; ++ks) {
        float av[8];
        *(float4*)(&av[0]) = *(const float4*)(pA + ks * 32);
        *(float4*)(&av[4]) = *(const float4*)(pA + ks * 32 + 4);
        bf8v ah, al;
#pragma unroll
        for (int j = 0; j < 8; ++j) {
            ushort h = to_bf(av[j]);
            ah[j] = (short)h;
            al[j] = (short)to_bf(av[j] - from_bf(h));
        }
#pragma unroll
        for (int ct = 0; ct < 8; ++ct) {
            bf8v bh = *(const bf8v*)(&Bs[0][ct * 16 + r16][ks * 32 + kg * 8]);
            bf8v bl = *(const bf8v*)(&Bs[1][ct * 16 + r16][ks * 32 + kg * 8]);
            acc[ct] = __builtin_amdgcn_mfma_f32_16x16x32_bf16(ah, bh, acc[ct], 0, 0, 0);
            acc[ct] = __builtin_amdgcn_mfma_f32_16x16x32_bf16(ah, bl, acc[ct], 0, 0, 0);
            acc[ct] = __builtin_amdgcn_mfma_f32_16x16x32_bf16(al, bh, acc[ct], 0, 0, 0);
        }
    }

    const int rbase = blockIdx.x * 64 + w * 16 + kg * 4;
#pragma unroll
    for (int r = 0; r < 4; ++r) {
        int row = rbase + r;
        if (row < M) {
            float sc = rowscale[row];
#pragma unroll
            for (int ct = 0; ct < 8; ++ct)
                C[(size_t)row * 128 + ct * 16 + r16] = to_bf(acc[ct][r] * sc);
        }
    }
}

// ---------------------------------------------------------------------------
// Aggregation over pre-scaled bf16 rows: v = di*(C[n] + sum C[s]) + b.
// RELU+fp32 out (H) or plain+bf16 out (PQ). One wave/node, lane = 2 features.
// Indices broadcast from one coalesced 64-wide load; 8 gathers in flight.
// ---------------------------------------------------------------------------
template <bool RELU, bool BF16OUT>
__global__ void gcn_agg_k(const ushort* __restrict__ Cb, const float* __restrict__ dinv,
                          const int* __restrict__ row_start, const int* __restrict__ cnt,
                          const int2* __restrict__ csr_se, const float* __restrict__ bias,
                          float* __restrict__ outf, ushort* __restrict__ outh, int n) {
    int wid = (int)((blockIdx.x * blockDim.x + threadIdx.x) >> 6);
    int lane = threadIdx.x & 63;
    if (wid >= n) return;
    float di = dinv[wid];
    int deg = cnt[wid];
    int rs = row_start[wid];
    ushort2 a = *(const ushort2*)(Cb + (size_t)wid * 128 + lane * 2);
    float ax = from_bf(a.x), ay = from_bf(a.y);
    int i = 0;
    while (i < deg) {
        int take = deg - i;
        if (take > 64) take = 64;
        int addr = rs + i + lane;
        int lim = rs + deg - 1;
        if (addr > lim) addr = lim;
        int vidx = csr_se[addr].x;
        int j = 0;
        for (; j + 8 <= take; j += 8) {
            int s0 = __shfl(vidx, j + 0), s1 = __shfl(vidx, j + 1);
            int s2 = __shfl(vidx, j + 2), s3 = __shfl(vidx, j + 3);
            int s4 = __shfl(vidx, j + 4), s5 = __shfl(vidx, j + 5);
            int s6 = __shfl(vidx, j + 6), s7 = __shfl(vidx, j + 7);
            ushort2 u0 = *(const ushort2*)(Cb + (size_t)s0 * 128 + lane * 2);
            ushort2 u1 = *(const ushort2*)(Cb + (size_t)s1 * 128 + lane * 2);
            ushort2 u2 = *(const ushort2*)(Cb + (size_t)s2 * 128 + lane * 2);
            ushort2 u3 = *(const ushort2*)(Cb + (size_t)s3 * 128 + lane * 2);
            ushort2 u4 = *(const ushort2*)(Cb + (size_t)s4 * 128 + lane * 2);
            ushort2 u5 = *(const ushort2*)(Cb + (size_t)s5 * 128 + lane * 2);
            ushort2 u6 = *(const ushort2*)(Cb + (size_t)s6 * 128 + lane * 2);
            ushort2 u7 = *(const ushort2*)(Cb + (size_t)s7 * 128 + lane * 2);
            ax += ((from_bf(u0.x) + from_bf(u1.x)) + (from_bf(u2.x) + from_bf(u3.x))) +
                  ((from_bf(u4.x) + from_bf(u5.x)) + (from_bf(u6.x) + from_bf(u7.x)));
            ay += ((from_bf(u0.y) + from_bf(u1.y)) + (from_bf(u2.y) + from_bf(u3.y))) +
                  ((from_bf(u4.y) + from_bf(u5.y)) + (from_bf(u6.y) + from_bf(u7.y)));
        }
        for (; j + 2 <= take; j += 2) {
            int s0 = __shfl(vidx, j + 0), s1 = __shfl(vidx, j + 1);
            ushort2 u0 = *(const ushort2*)(Cb + (size_t)s0 * 128 + lane * 2);
            ushort2 u1 = *(const ushort2*)(Cb + (size_t)s1 * 128 + lane * 2);
            ax += from_bf(u0.x) + from_bf(u1.x);
            ay += from_bf(u0.y) + from_bf(u1.y);
        }
        if (j < take) {
            int s = __shfl(vidx, j);
            ushort2 u = *(const ushort2*)(Cb + (size_t)s * 128 + lane * 2);
            ax += from_bf(u.x);
            ay += from_bf(u.y);
        }
        i += take;
    }
    float2 b = ((const float2*)bias)[lane];
    ax = fmaf(ax, di, b.x);
    ay = fmaf(ay, di, b.y);
    if constexpr (RELU) {
        ax = fmaxf(ax, 0.f);
        ay = fmaxf(ay, 0.f);
    }
    if constexpr (BF16OUT) {
        ushort2 h;
        h.x = to_bf(ax);
        h.y = to_bf(ay);
        ((ushort2*)outh)[(size_t)wid * 64 + lane] = h;
    } else {
        float2 r; r.x = ax; r.y = ay;
        ((float2*)outf)[(size_t)wid * 64 + lane] = r;
    }
}

// ---------------------------------------------------------------------------
// Edge op, per-dst-node over bf16 PQ: out[eid] = relu(P[s]+Q[d]+bm1).w2 + b2.
// Q[d]+bm1 in regs; P[s] gather is 128B/edge (1 cache line). 16 lanes/edge.
// ---------------------------------------------------------------------------
__global__ __launch_bounds__(256) void edge_dec_k(
    const ushort* __restrict__ PQ, const int* __restrict__ row_start,
    const int* __restrict__ cnt, const int2* __restrict__ csr_se,
    const float* __restrict__ bm1, const float* __restrict__ w2,
    const float* __restrict__ bm2, float* __restrict__ out, int n) {
    int wid = (int)((blockIdx.x * blockDim.x + threadIdx.x) >> 6);
    int lane = threadIdx.x & 63;
    if (wid >= n) return;
    int deg = cnt[wid];
    if (deg == 0) return;
    int rs = row_start[wid];
    const int sub = lane >> 4;
    const int q = lane & 15;

    const float4 b1v = ((const float4*)bm1)[q];
    const float4 w2v = ((const float4*)w2)[q];
    const float b2 = bm2[0];
    ushort4 Qu = *(const ushort4*)(PQ + (size_t)wid * 128 + 64 + q * 4);
    float4 bq;
    bq.x = from_bf(Qu.x) + b1v.x; bq.y = from_bf(Qu.y) + b1v.y;
    bq.z = from_bf(Qu.z) + b1v.z; bq.w = from_bf(Qu.w) + b1v.w;

    int i = 0;
    while (i < deg) {
        int take = deg - i;
        if (take > 64) take = 64;
        int addr = rs + i + lane;
        int lim = rs + deg - 1;
        if (addr > lim) addr = lim;
        int2 se = csr_se[addr];
        for (int j = 0; j < take; j += 8) {
            int ia = j + sub;
            int ib = j + 4 + sub;
            bool aa = ia < take;
            bool ab = ib < take;
            int sa = __shfl(se.x, aa ? ia : 0);
            int ea = __shfl(se.y, aa ? ia : 0);
            int sb = __shfl(se.x, ab ? ib : 0);
            int eb = __shfl(se.y, ab ? ib : 0);
            ushort4 pua = *(const ushort4*)(PQ + (size_t)sa * 128 + q * 4);
            ushort4 pub = *(const ushort4*)(PQ + (size_t)sb * 128 + q * 4);
            float ha0 = fmaxf(from_bf(pua.x) + bq.x, 0.f);
            float ha1 = fmaxf(from_bf(pua.y) + bq.y, 0.f);
            float ha2 = fmaxf(from_bf(pua.z) + bq.z, 0.f);
            float ha3 = fmaxf(from_bf(pua.w) + bq.w, 0.f);
            float hb0 = fmaxf(from_bf(pub.x) + bq.x, 0.f);
            float hb1 = fmaxf(from_bf(pub.y) + bq.y, 0.f);
            float hb2 = fmaxf(from_bf(pub.z) + bq.z, 0.f);
            float hb3 = fmaxf(from_bf(pub.w) + bq.w, 0.f);
            float va = fmaf(ha0, w2v.x, fmaf(ha1, w2v.y, fmaf(ha2, w2v.z, ha3 * w2v.w)));
            float vb = fmaf(hb0, w2v.x, fmaf(hb1, w2v.y, fmaf(hb2, w2v.z, hb3 * w2v.w)));
            va += __shfl_xor(va, 8, 16);
            va += __shfl_xor(va, 4, 16);
            va += __shfl_xor(va, 2, 16);
            va += __shfl_xor(va, 1, 16);
            vb += __shfl_xor(vb, 8, 16);
            vb += __shfl_xor(vb, 4, 16);
            vb += __shfl_xor(vb, 2, 16);
            vb += __shfl_xor(vb, 1, 16);
            if (aa && q == 0) out[ea] = va + b2;
            if (ab && q == 0) out[eb] = vb + b2;
        }
        i += take;
    }
}

// ---------------------------------------------------------------------------

extern "C" void kernel_launch(void* const* d_in, const int* in_sizes, int n_in,
                              void* d_out, int out_size, void* d_ws, size_t ws_size,
                              hipStream_t stream) {
    const float* X   = (const float*)d_in[0];
    const int*  edges = (const int*)d_in[1];
    const float* Wg1 = (const float*)d_in[2];
    const float* bg1 = (const float*)d_in[3];
    const float* Wg2 = (const float*)d_in[4];
    const float* bg2 = (const float*)d_in[5];
    const float* Wm1 = (const float*)d_in[6];
    const float* bm1 = (const float*)d_in[7];
    const float* Wm2 = (const float*)d_in[8];
    const float* bm2 = (const float*)d_in[9];
    float* out = (float*)d_out;

    const int N = in_sizes[0] / 128;
    const int E = in_sizes[1] / 2;
    const int* esrc = edges;
    const int* edst = edges + E;

    char* p = (char*)d_ws;
    auto alloc = [&](size_t nbytes) {
        void* r = (void*)p;
        p += (nbytes + 255) & ~(size_t)255;
        return r;
    };
    float* H      = (float*)alloc((size_t)N * 128 * 4);   // agg1 out (fp32)
    ushort* Cb    = (ushort*)alloc((size_t)N * 128 * 2);  // gemm out (bf16), reused
    ushort* PQ    = (ushort*)alloc((size_t)N * 128 * 2);  // agg2 out (bf16)
    float* dinv   = (float*)alloc((size_t)N * 4);
    int* cnt      = (int*)alloc((size_t)N * 4);
    int* rowst    = (int*)alloc((size_t)N * 4);
    int* cursor   = (int*)alloc((size_t)N * 4);
    int* bsum     = (int*)alloc(1024);
    ushort* Wg1th = (ushort*)alloc(128 * 128 * 2);
    ushort* Wg1tl = (ushort*)alloc(128 * 128 * 2);
    ushort* Wfth  = (ushort*)alloc(128 * 128 * 2);
    ushort* Wftl  = (ushort*)alloc(128 * 128 * 2);
    float* bcat   = (float*)alloc(128 * 4);
    int2* csr_se  = (int2*)alloc((size_t)E * 8);
    (void)ws_size; (void)n_in; (void)out_size;

    const int gE = (E + 255) / 256;
    const int gN = (N + 255) / 256;
    const int nb = (N + 1023) / 1024;
    const int gM64 = (N + 63) / 64;
    const int gAgg = (N * 64 + 255) / 256;

    hipMemsetAsync(cnt, 0, (size_t)N * 4, stream);
    deg_count_k<<<gE, 256, 0, stream>>>(edst, cnt, E);
    deg_inv_k<<<gN, 256, 0, stream>>>(cnt, dinv, N);
    scan_a_k<<<nb, 256, 0, stream>>>(cnt, rowst, bsum, N);
    scan_b_k<<<1, 256, 0, stream>>>(bsum, nb);
    scan_c_k<<<gN, 256, 0, stream>>>(rowst, bsum, cursor, N);
    csr_fill_k<<<gE, 256, 0, stream>>>(esrc, edst, cursor, csr_se, E);
    w1t_split_k<<<64, 256, 0, stream>>>(Wg1, Wg1th, Wg1tl);
    wfold_split_k<<<65, 256, 0, stream>>>(Wg2, bg2, Wm1, Wfth, Wftl, bcat);

    // Cb = bf16( dinv * (X @ Wg1) )
    gemm_mfma_k<<<gM64, 256, 0, stream>>>(X, Wg1th, Wg1tl, dinv, Cb, N);
    // H = relu(dinv*(self+sum) + bg1)  (fp32)
    gcn_agg_k<true, false><<<gAgg, 256, 0, stream>>>(Cb, dinv, rowst, cnt, csr_se, bg1,
                                                     H, nullptr, N);
    // Cb = bf16( dinv * (H @ Wfold) )
    gemm_mfma_k<<<gM64, 256, 0, stream>>>(H, Wfth, Wftl, dinv, Cb, N);
    // PQ = bf16( dinv*(self+sum) + bcat )
    gcn_agg_k<false, true><<<gAgg, 256, 0, stream>>>(Cb, dinv, rowst, cnt, csr_se, bcat,
                                                     nullptr, PQ, N);
    // out[eid] = relu(P[s]+Q[d]+bm1).w2 + b2
    edge_dec_k<<<gAgg, 256, 0, stream>>>(PQ, rowst, cnt, csr_se, bm1, Wm2, bm2, out, N);
}